// Round 1
// baseline (3993.052 us; speedup 1.0000x reference)
//
#include <hip/hip_runtime.h>
#include <cstddef>

#define TSTEPS 128
#define BATCH  256
#define DIN    600
#define NR     6
#define KACT   4
#define DH     100
#define DK     64
#define DV     400
#define G3     300
#define LD1    512    // PRE1 row stride: [kx(64) | vx(400) | pad(48)]
#define LDG    1920   // GX row stride: [gi(1800) | pad(120)]

// ---------- W1[600][512] = [Wk | Wv | 0] ----------
__global__ __launch_bounds__(256) void build_w1(const float* __restrict__ Wk,
                                                const float* __restrict__ Wv,
                                                float* __restrict__ W1) {
  int idx = blockIdx.x * 256 + threadIdx.x;
  if (idx >= DIN * LD1) return;
  int d = idx >> 9, c = idx & (LD1 - 1);
  float v = 0.f;
  if (c < DK)            v = Wk[d * DK + c];
  else if (c < DK + DV)  v = Wv[d * DV + (c - DK)];
  W1[idx] = v;
}

// ---------- WT[400][1920]: WT[v][n*300+j] = W_ih[n][v][j], zero pad ----------
__global__ __launch_bounds__(256) void build_wt(const float* __restrict__ Wih,
                                                float* __restrict__ WT) {
  int idx = blockIdx.x * 256 + threadIdx.x;
  if (idx >= DV * LDG) return;
  int v = idx / LDG, c = idx - v * LDG;
  float w = 0.f;
  if (c < NR * G3) { int n = c / G3, j = c - n * G3; w = Wih[(n * DV + v) * G3 + j]; }
  WT[idx] = w;
}

// ---------- generic fp32 GEMM: C[M][ldc] = A[M][lda(K...)] * B[K][ldb] ----------
// M multiple of 128 (grid.x = M/128), N multiple of 128 (grid.y = N/128), K multiple of 8.
__global__ __launch_bounds__(256) void sgemm_k(const float* __restrict__ A, int lda,
                                               const float* __restrict__ B, int ldb,
                                               float* __restrict__ C, int ldc, int K) {
  __shared__ float As[8][132];
  __shared__ float Bs[8][128];
  const int tid = threadIdx.x;
  const int tx = tid & 15, ty = tid >> 4;
  const size_t m0 = (size_t)blockIdx.x * 128, n0 = (size_t)blockIdx.y * 128;
  const int arow = tid >> 1, akq = (tid & 1) * 4;
  const int brow = tid >> 5, bcol = (tid & 31) * 4;
  const float* Ap = A + (m0 + arow) * (size_t)lda + akq;
  const float* Bp = B + (size_t)brow * ldb + n0 + bcol;

  float acc[8][8];
#pragma unroll
  for (int i = 0; i < 8; ++i)
#pragma unroll
    for (int j = 0; j < 8; ++j) acc[i][j] = 0.f;

  for (int k0 = 0; k0 < K; k0 += 8) {
    float4 av = *(const float4*)(Ap + k0);
    float4 bv = *(const float4*)(Bp + (size_t)k0 * ldb);
    __syncthreads();
    As[akq + 0][arow] = av.x;
    As[akq + 1][arow] = av.y;
    As[akq + 2][arow] = av.z;
    As[akq + 3][arow] = av.w;
    *(float4*)&Bs[brow][bcol] = bv;
    __syncthreads();
#pragma unroll
    for (int k = 0; k < 8; ++k) {
      float a[8], b[8];
#pragma unroll
      for (int i = 0; i < 8; ++i) a[i] = As[k][ty * 8 + i];
#pragma unroll
      for (int j = 0; j < 8; ++j) b[j] = Bs[k][tx * 8 + j];
#pragma unroll
      for (int i = 0; i < 8; ++i)
#pragma unroll
        for (int j = 0; j < 8; ++j) acc[i][j] += a[i] * b[j];
    }
  }

  float* Cp = C + (m0 + (size_t)ty * 8) * ldc + n0 + tx * 8;
#pragma unroll
  for (int i = 0; i < 8; ++i) {
    float4 v0 = make_float4(acc[i][0], acc[i][1], acc[i][2], acc[i][3]);
    float4 v1 = make_float4(acc[i][4], acc[i][5], acc[i][6], acc[i][7]);
    *(float4*)(Cp + (size_t)i * ldc)     = v0;
    *(float4*)(Cp + (size_t)i * ldc + 4) = v1;
  }
}

// ---------- sequential RIMs scan: 64 blocks x 4 batch elems, h in LDS ----------
__global__ __launch_bounds__(256) void rim_scan(
    const float* __restrict__ PRE1, const float* __restrict__ GX,
    const float* __restrict__ Wq,   const float* __restrict__ Whh,
    const float* __restrict__ bih,  const float* __restrict__ bhh,
    float* __restrict__ out, float* __restrict__ hstate,
    int t0, int tc, int first) {
  __shared__ float hl[4][NR][DH];     // 9.6 KB
  __shared__ float kx[4][DK];         // 1 KB
  __shared__ float qs[4][NR][DK];     // 6 KB
  __shared__ float gh[4][NR * G3];    // 28.8 KB
  __shared__ float pp[4][NR];
  __shared__ float pm[4][NR];
  const int tid = threadIdx.x;
  const int b0 = blockIdx.x * 4;

  if (first) {
    for (int i = tid; i < 4 * NR * DH; i += 256) ((float*)hl)[i] = 0.f;
  } else {
    for (int i = tid; i < 4 * NR * DH; i += 256) ((float*)hl)[i] = hstate[(size_t)b0 * 600 + i];
  }
  __syncthreads();

  for (int tl = 0; tl < tc; ++tl) {
    const int t = t0 + tl;
    // ---- A: load kx rows for the 4 batches ----
    {
      int b = tid >> 6, k = tid & 63;
      kx[b][k] = PRE1[((size_t)tl * 256 + b0 + b) * LD1 + k];
    }
    __syncthreads();
    // ---- B: q[b][n][k] = sum_h h[b][n][h] * Wq[n][h][k] (weight-stationary over b) ----
    for (int pair = tid; pair < NR * DK; pair += 256) {
      int k = pair & 63, n = pair >> 6;
      const float* wq = Wq + (size_t)n * (DH * DK) + k;
      float a0 = 0.f, a1 = 0.f, a2 = 0.f, a3 = 0.f;
      for (int h = 0; h < DH; ++h) {
        float w = wq[(size_t)h * DK];
        a0 += hl[0][n][h] * w;
        a1 += hl[1][n][h] * w;
        a2 += hl[2][n][h] * w;
        a3 += hl[3][n][h] * w;
      }
      qs[0][n][k] = a0; qs[1][n][k] = a1; qs[2][n][k] = a2; qs[3][n][k] = a3;
    }
    __syncthreads();
    // ---- C1: scores -> p_in (softmax([s,0]) with max-subtraction, like jax.nn.softmax) ----
    if (tid < 24) {
      int b = tid / 6, n = tid - (tid / 6) * 6;
      float s = 0.f;
      for (int k = 0; k < DK; ++k) s += qs[b][n][k] * kx[b][k];
      s *= 0.125f;
      float m  = s > 0.f ? s : 0.f;
      float e0 = expf(s - m);
      float e1 = expf(-m);
      pp[b][n] = e0 / (e0 + e1);
    }
    __syncthreads();
    // ---- C2: stable top-k mask (ties -> lower index, matching lax.top_k) ----
    if (tid < 24) {
      int b = tid / 6, n = tid - (tid / 6) * 6;
      float p = pp[b][n];
      int cnt = 0;
      for (int m = 0; m < NR; ++m) {
        float q = pp[b][m];
        if (q > p || (q == p && m < n)) ++cnt;
      }
      pm[b][n] = (cnt < KACT) ? 1.f : 0.f;
    }
    __syncthreads();
    // ---- D: gh[b][n*300+j] = sum_h h[b][n][h] * Whh[n][h][j], col-quad stationary ----
    for (int qd = tid; qd < 450; qd += 256) {
      int col = qd * 4;
      int n = col / G3;
      int j = col - n * G3;
      const float* wb = Whh + (size_t)n * (DH * G3) + j;
      float a0x=0,a0y=0,a0z=0,a0w=0, a1x=0,a1y=0,a1z=0,a1w=0;
      float a2x=0,a2y=0,a2z=0,a2w=0, a3x=0,a3y=0,a3z=0,a3w=0;
      for (int h = 0; h < DH; ++h) {
        const float* w = wb + (size_t)h * G3;
        float w0 = w[0], w1 = w[1], w2 = w[2], w3 = w[3];
        float h0 = hl[0][n][h], h1 = hl[1][n][h], h2 = hl[2][n][h], h3 = hl[3][n][h];
        a0x += h0*w0; a0y += h0*w1; a0z += h0*w2; a0w += h0*w3;
        a1x += h1*w0; a1y += h1*w1; a1z += h1*w2; a1w += h1*w3;
        a2x += h2*w0; a2y += h2*w1; a2z += h2*w2; a2w += h2*w3;
        a3x += h3*w0; a3y += h3*w1; a3z += h3*w2; a3w += h3*w3;
      }
      gh[0][col] = a0x; gh[0][col+1] = a0y; gh[0][col+2] = a0z; gh[0][col+3] = a0w;
      gh[1][col] = a1x; gh[1][col+1] = a1y; gh[1][col+2] = a1z; gh[1][col+3] = a1w;
      gh[2][col] = a2x; gh[2][col+1] = a2y; gh[2][col+2] = a2z; gh[2][col+3] = a2w;
      gh[3][col] = a3x; gh[3][col+1] = a3y; gh[3][col+2] = a3z; gh[3][col+3] = a3w;
    }
    __syncthreads();
    // ---- E: GRU pointwise + state update + output ----
    for (int u = tid; u < 4 * NR * DH; u += 256) {
      int hh = u % DH;
      int n  = (u / DH) % NR;
      int b  = u / (NR * DH);
      int jr = n * G3 + hh;
      const float* gxr = GX + ((size_t)tl * 256 + b0 + b) * LDG;
      float p  = pp[b][n];
      float gr = gh[b][jr]           + bhh[jr];
      float gz = gh[b][jr + DH]      + bhh[jr + DH];
      float gn = gh[b][jr + 2 * DH]  + bhh[jr + 2 * DH];
      float ir  = p * gxr[jr]          + bih[jr];
      float iz  = p * gxr[jr + DH]     + bih[jr + DH];
      float inn = p * gxr[jr + 2 * DH] + bih[jr + 2 * DH];
      float r  = 1.f / (1.f + expf(-(ir + gr)));
      float z  = 1.f / (1.f + expf(-(iz + gz)));
      float nn = tanhf(inn + r * gn);
      float hprev = hl[b][n][hh];
      float hnew  = (1.f - z) * nn + z * hprev;
      float m = pm[b][n];
      out[(((size_t)t * BATCH + b0 + b) * NR + n) * DH + hh] = m * hnew;
      hl[b][n][hh] = (m > 0.f) ? hnew : hprev;
    }
    __syncthreads();
  }
  for (int i = tid; i < 4 * NR * DH; i += 256) hstate[(size_t)b0 * 600 + i] = ((float*)hl)[i];
}

extern "C" void kernel_launch(void* const* d_in, const int* in_sizes, int n_in,
                              void* d_out, int out_size, void* d_ws, size_t ws_size,
                              hipStream_t stream) {
  const float* x   = (const float*)d_in[0];
  const float* Wq  = (const float*)d_in[1];
  const float* Wk  = (const float*)d_in[2];
  const float* Wv  = (const float*)d_in[3];
  const float* Wih = (const float*)d_in[4];
  const float* Whh = (const float*)d_in[5];
  const float* bih = (const float*)d_in[6];
  const float* bhh = (const float*)d_in[7];
  float* out = (float*)d_out;
  char* ws = (char*)d_ws;

  const size_t W1_BYTES = (size_t)DIN * LD1 * 4;    // 1,228,800
  const size_t WT_BYTES = (size_t)DV * LDG * 4;     // 3,072,000
  const size_t H_BYTES  = (size_t)BATCH * 600 * 4;  // 614,400
  const size_t FIXED = W1_BYTES + WT_BYTES + H_BYTES;
  const size_t PER_STEP = (size_t)BATCH * (LD1 + LDG) * 4;  // 2,490,368

  float* W1     = (float*)ws;
  float* WT     = (float*)(ws + W1_BYTES);
  float* hstate = (float*)(ws + W1_BYTES + WT_BYTES);

  long long avail = (long long)ws_size - (long long)FIXED;
  int TC = 1;
  if (avail > 0) {
    long long t = avail / (long long)PER_STEP;
    TC = (int)(t < 1 ? 1 : (t > TSTEPS ? TSTEPS : t));
  }
  float* PRE1 = (float*)(ws + FIXED);
  float* GXb  = (float*)(ws + FIXED + (size_t)TC * BATCH * LD1 * 4);

  build_w1<<<(DIN * LD1) / 256, 256, 0, stream>>>(Wk, Wv, W1);
  build_wt<<<(DV * LDG) / 256, 256, 0, stream>>>(Wih, WT);

  for (int t0 = 0; t0 < TSTEPS; ) {
    int tc = TSTEPS - t0 < TC ? TSTEPS - t0 : TC;
    dim3 g1(tc * 2, LD1 / 128);
    sgemm_k<<<g1, 256, 0, stream>>>(x + (size_t)t0 * BATCH * DIN, DIN, W1, LD1, PRE1, LD1, DIN);
    dim3 g2(tc * 2, LDG / 128);
    sgemm_k<<<g2, 256, 0, stream>>>(PRE1 + DK, LD1, WT, LDG, GXb, LDG, DV);
    rim_scan<<<BATCH / 4, 256, 0, stream>>>(PRE1, GXb, Wq, Whh, bih, bhh, out, hstate,
                                            t0, tc, t0 == 0 ? 1 : 0);
    t0 += tc;
  }
}

// Round 2
// 3012.117 us; speedup vs baseline: 1.3257x; 1.3257x over previous
//
#include <hip/hip_runtime.h>
#include <cstddef>

#define TSTEPS 128
#define BATCH  256
#define DIN    600
#define NR     6
#define KACT   4
#define DH     100
#define DK     64
#define DV     400
#define G3     300
#define LD1    512    // PRE1 row stride: [kx(64) | vx(400) | pad(48)]
#define LDG    1920   // GX row stride: [gi(1800) | pad(120)]

// ---------- W1[600][512] = [Wk | Wv | 0] ----------
__global__ __launch_bounds__(256) void build_w1(const float* __restrict__ Wk,
                                                const float* __restrict__ Wv,
                                                float* __restrict__ W1) {
  int idx = blockIdx.x * 256 + threadIdx.x;
  if (idx >= DIN * LD1) return;
  int d = idx >> 9, c = idx & (LD1 - 1);
  float v = 0.f;
  if (c < DK)            v = Wk[d * DK + c];
  else if (c < DK + DV)  v = Wv[d * DV + (c - DK)];
  W1[idx] = v;
}

// ---------- WT[400][1920]: WT[v][n*300+j] = W_ih[n][v][j], zero pad ----------
__global__ __launch_bounds__(256) void build_wt(const float* __restrict__ Wih,
                                                float* __restrict__ WT) {
  int idx = blockIdx.x * 256 + threadIdx.x;
  if (idx >= DV * LDG) return;
  int v = idx / LDG, c = idx - v * LDG;
  float w = 0.f;
  if (c < NR * G3) { int n = c / G3, j = c - n * G3; w = Wih[(n * DV + v) * G3 + j]; }
  WT[idx] = w;
}

// ---------- generic fp32 GEMM: C[M][ldc] = A[M][lda(K...)] * B[K][ldb] ----------
__global__ __launch_bounds__(256) void sgemm_k(const float* __restrict__ A, int lda,
                                               const float* __restrict__ B, int ldb,
                                               float* __restrict__ C, int ldc, int K) {
  __shared__ float As[8][132];
  __shared__ float Bs[8][128];
  const int tid = threadIdx.x;
  const int tx = tid & 15, ty = tid >> 4;
  const size_t m0 = (size_t)blockIdx.x * 128, n0 = (size_t)blockIdx.y * 128;
  const int arow = tid >> 1, akq = (tid & 1) * 4;
  const int brow = tid >> 5, bcol = (tid & 31) * 4;
  const float* Ap = A + (m0 + arow) * (size_t)lda + akq;
  const float* Bp = B + (size_t)brow * ldb + n0 + bcol;

  float acc[8][8];
#pragma unroll
  for (int i = 0; i < 8; ++i)
#pragma unroll
    for (int j = 0; j < 8; ++j) acc[i][j] = 0.f;

  for (int k0 = 0; k0 < K; k0 += 8) {
    float4 av = *(const float4*)(Ap + k0);
    float4 bv = *(const float4*)(Bp + (size_t)k0 * ldb);
    __syncthreads();
    As[akq + 0][arow] = av.x;
    As[akq + 1][arow] = av.y;
    As[akq + 2][arow] = av.z;
    As[akq + 3][arow] = av.w;
    *(float4*)&Bs[brow][bcol] = bv;
    __syncthreads();
#pragma unroll
    for (int k = 0; k < 8; ++k) {
      float a[8], b[8];
#pragma unroll
      for (int i = 0; i < 8; ++i) a[i] = As[k][ty * 8 + i];
#pragma unroll
      for (int j = 0; j < 8; ++j) b[j] = Bs[k][tx * 8 + j];
#pragma unroll
      for (int i = 0; i < 8; ++i)
#pragma unroll
        for (int j = 0; j < 8; ++j) acc[i][j] += a[i] * b[j];
    }
  }

  float* Cp = C + (m0 + (size_t)ty * 8) * ldc + n0 + tx * 8;
#pragma unroll
  for (int i = 0; i < 8; ++i) {
    float4 v0 = make_float4(acc[i][0], acc[i][1], acc[i][2], acc[i][3]);
    float4 v1 = make_float4(acc[i][4], acc[i][5], acc[i][6], acc[i][7]);
    *(float4*)(Cp + (size_t)i * ldc)     = v0;
    *(float4*)(Cp + (size_t)i * ldc + 4) = v1;
  }
}

// ---------- RIMs scan: block = (batch-group of 8, rim). 192 blocks, weights in LDS ----------
__global__ __launch_bounds__(256) void rim_scan(
    const float* __restrict__ PRE1, const float* __restrict__ GX,
    const float* __restrict__ Wq,   const float* __restrict__ Whh,
    const float* __restrict__ bih,  const float* __restrict__ bhh,
    float* __restrict__ out, float* __restrict__ hstate,
    float* __restrict__ pbuf, int* __restrict__ cnt,
    int t0, int tc, int first) {
  __shared__ __align__(16) float Wl[DH][G3];    // 120.0 KB  Whh[n], stationary
  __shared__ __align__(16) float Wql[DH][DK];   //  25.6 KB  Wq[n], stationary
  __shared__ __align__(16) float hl[DH][8];     //   3.2 KB  h transposed [hh][b]
  __shared__ __align__(16) float kxl[8][68];    //   2.1 KB  (pad 68 -> conflict-free score)
  __shared__ __align__(16) float ql[8][68];     //   2.1 KB
  __shared__ float pl[8][NR];
  __shared__ float bihl[G3], bhhl[G3];

  const int tid = threadIdx.x;
  const int g = blockIdx.x & 31;   // batch group
  const int n = blockIdx.x >> 5;   // rim

  // ---- stage per-rim weights into LDS (once) ----
  {
    const float* wsrc = Whh + (size_t)n * (DH * G3);
    for (int i = tid * 4; i < DH * G3; i += 1024)
      *(float4*)((float*)Wl + i) = *(const float4*)(wsrc + i);
    const float* qsrc = Wq + (size_t)n * (DH * DK);
    for (int i = tid * 4; i < DH * DK; i += 1024)
      *(float4*)((float*)Wql + i) = *(const float4*)(qsrc + i);
    if (tid < G3) { bihl[tid] = bih[n * G3 + tid]; bhhl[tid] = bhh[n * G3 + tid]; }
    if (first) {
      for (int i = tid; i < 8 * DH; i += 256) hl[i >> 3][i & 7] = 0.f;
    } else {
      for (int i = tid; i < 8 * DH; i += 256) {
        int b = i & 7, hh = i >> 3;
        hl[hh][b] = hstate[((size_t)(g * 8 + b) * NR + n) * DH + hh];
      }
    }
  }
  __syncthreads();

  const int half = tid >> 7;       // 0/1 -> batches 0-3 / 4-7
  const int ho = tid & 127;        // output hidden index (valid < 100)
  const bool act_t = ho < DH;
  const int bbase = half * 4;
  const int kq = tid & 63, bp = tid >> 6;  // q-phase mapping

  for (int tl = 0; tl < tc; ++tl) {
    const int t = t0 + tl;
    const int par = t & 1;

    // ---- prefetch this step's GX rows into registers (hidden under gh) ----
    float gx[4][3];
    if (act_t) {
#pragma unroll
      for (int b = 0; b < 4; ++b) {
        const float* gr = GX + ((size_t)tl * BATCH + g * 8 + bbase + b) * LDG + n * G3;
        gx[b][0] = gr[ho]; gx[b][1] = gr[ho + DH]; gx[b][2] = gr[ho + 2 * DH];
      }
    }

    // ---- kx load + q = h @ Wq (bit-identical order to round 1) ----
    kxl[bp][kq]     = PRE1[((size_t)tl * BATCH + g * 8 + bp) * LD1 + kq];
    kxl[bp + 4][kq] = PRE1[((size_t)tl * BATCH + g * 8 + bp + 4) * LD1 + kq];
    {
      float a0 = 0.f, a1 = 0.f;
      for (int hh = 0; hh < DH; ++hh) {
        float w = Wql[hh][kq];
        a0 += hl[hh][bp] * w;
        a1 += hl[hh][bp + 4] * w;
      }
      ql[bp][kq] = a0; ql[bp + 4][kq] = a1;
    }
    __syncthreads();

    // ---- score -> p_in, publish to peers ----
    if (tid < 8) {
      float s = 0.f;
      for (int k = 0; k < DK; ++k) s += ql[tid][k] * kxl[tid][k];
      s *= 0.125f;
      float m = s > 0.f ? s : 0.f;
      float e0 = expf(s - m), e1 = expf(-m);
      float p = e0 / (e0 + e1);
      __hip_atomic_store(&pbuf[((par * 32 + g) * NR + n) * 8 + tid], p,
                         __ATOMIC_RELAXED, __HIP_MEMORY_SCOPE_AGENT);
    }
    if (tid == 0) {
      __threadfence();
      __hip_atomic_fetch_add(&cnt[g], 1, __ATOMIC_RELEASE, __HIP_MEMORY_SCOPE_AGENT);
    }

    // ---- gh = h @ Whh from LDS (overlaps peer latency) ----
    float acc[4][3];
#pragma unroll
    for (int b = 0; b < 4; ++b) { acc[b][0] = 0.f; acc[b][1] = 0.f; acc[b][2] = 0.f; }
    if (act_t) {
#pragma unroll 2
      for (int hh = 0; hh < DH; ++hh) {
        float w0 = Wl[hh][ho], w1 = Wl[hh][ho + DH], w2 = Wl[hh][ho + 2 * DH];
        float4 hv = *(const float4*)&hl[hh][bbase];
        acc[0][0] += hv.x * w0; acc[0][1] += hv.x * w1; acc[0][2] += hv.x * w2;
        acc[1][0] += hv.y * w0; acc[1][1] += hv.y * w1; acc[1][2] += hv.y * w2;
        acc[2][0] += hv.z * w0; acc[2][1] += hv.z * w1; acc[2][2] += hv.z * w2;
        acc[3][0] += hv.w * w0; acc[3][1] += hv.w * w1; acc[3][2] += hv.w * w2;
      }
    }

    // ---- wait for all 6 rims of this group, gather p ----
    {
      const int target = 6 * (t + 1);
      while (__hip_atomic_load(&cnt[g], __ATOMIC_ACQUIRE, __HIP_MEMORY_SCOPE_AGENT) < target)
        __builtin_amdgcn_s_sleep(2);
    }
    if (tid < 48) {
      int b = tid & 7, r = tid >> 3;
      pl[b][r] = __hip_atomic_load(&pbuf[((par * 32 + g) * NR + r) * 8 + b],
                                   __ATOMIC_RELAXED, __HIP_MEMORY_SCOPE_AGENT);
    }
    __syncthreads();

    // ---- top-k mask + GRU pointwise + state update ----
    if (act_t) {
#pragma unroll
      for (int b = 0; b < 4; ++b) {
        const int bb = bbase + b;
        float p = pl[bb][n];
        int c = 0;
#pragma unroll
        for (int r = 0; r < NR; ++r) {
          float q = pl[bb][r];
          if (q > p || (q == p && r < n)) ++c;
        }
        float m = (c < KACT) ? 1.f : 0.f;
        float grv = acc[b][0] + bhhl[ho];
        float gzv = acc[b][1] + bhhl[ho + DH];
        float gnv = acc[b][2] + bhhl[ho + 2 * DH];
        float ir  = p * gx[b][0] + bihl[ho];
        float iz  = p * gx[b][1] + bihl[ho + DH];
        float inn = p * gx[b][2] + bihl[ho + 2 * DH];
        float rr = 1.f / (1.f + expf(-(ir + grv)));
        float zz = 1.f / (1.f + expf(-(iz + gzv)));
        float nn = tanhf(inn + rr * gnv);
        float hprev = hl[ho][bb];
        float hnew = (1.f - zz) * nn + zz * hprev;
        out[(((size_t)t * BATCH + g * 8 + bb) * NR + n) * DH + ho] = m * hnew;
        hl[ho][bb] = (m > 0.f) ? hnew : hprev;
      }
    }
    __syncthreads();
  }

  for (int i = tid; i < 8 * DH; i += 256) {
    int b = i & 7, hh = i >> 3;
    hstate[((size_t)(g * 8 + b) * NR + n) * DH + hh] = hl[hh][b];
  }
}

extern "C" void kernel_launch(void* const* d_in, const int* in_sizes, int n_in,
                              void* d_out, int out_size, void* d_ws, size_t ws_size,
                              hipStream_t stream) {
  const float* x   = (const float*)d_in[0];
  const float* Wq  = (const float*)d_in[1];
  const float* Wk  = (const float*)d_in[2];
  const float* Wv  = (const float*)d_in[3];
  const float* Wih = (const float*)d_in[4];
  const float* Whh = (const float*)d_in[5];
  const float* bih = (const float*)d_in[6];
  const float* bhh = (const float*)d_in[7];
  float* out = (float*)d_out;
  char* ws = (char*)d_ws;

  const size_t W1_BYTES   = (size_t)DIN * LD1 * 4;     // 1,228,800
  const size_t WT_BYTES   = (size_t)DV * LDG * 4;      // 3,072,000
  const size_t H_BYTES    = (size_t)BATCH * 600 * 4;   //   614,400
  const size_t CNT_BYTES  = 256;                       // 32 ints, padded
  const size_t PBUF_BYTES = 2 * 32 * NR * 8 * 4;       //    12,288
  const size_t FIXED = W1_BYTES + WT_BYTES + H_BYTES + CNT_BYTES + PBUF_BYTES;
  const size_t PER_STEP = (size_t)BATCH * (LD1 + LDG) * 4;  // 2,490,368

  float* W1     = (float*)ws;
  float* WT     = (float*)(ws + W1_BYTES);
  float* hstate = (float*)(ws + W1_BYTES + WT_BYTES);
  int*   cnt    = (int*)  (ws + W1_BYTES + WT_BYTES + H_BYTES);
  float* pbuf   = (float*)(ws + W1_BYTES + WT_BYTES + H_BYTES + CNT_BYTES);

  long long avail = (long long)ws_size - (long long)FIXED;
  int TC = 1;
  if (avail > 0) {
    long long t = avail / (long long)PER_STEP;
    TC = (int)(t < 1 ? 1 : (t > TSTEPS ? TSTEPS : t));
  }
  float* PRE1 = (float*)(ws + FIXED);
  float* GXb  = (float*)(ws + FIXED + (size_t)TC * BATCH * LD1 * 4);

  hipMemsetAsync(cnt, 0, CNT_BYTES, stream);
  build_w1<<<(DIN * LD1) / 256, 256, 0, stream>>>(Wk, Wv, W1);
  build_wt<<<(DV * LDG) / 256, 256, 0, stream>>>(Wih, WT);

  for (int t0 = 0; t0 < TSTEPS; ) {
    int tc = TSTEPS - t0 < TC ? TSTEPS - t0 : TC;
    dim3 g1(tc * 2, LD1 / 128);
    sgemm_k<<<g1, 256, 0, stream>>>(x + (size_t)t0 * BATCH * DIN, DIN, W1, LD1, PRE1, LD1, DIN);
    dim3 g2(tc * 2, LDG / 128);
    sgemm_k<<<g2, 256, 0, stream>>>(PRE1 + DK, LD1, WT, LDG, GXb, LDG, DV);
    rim_scan<<<32 * NR, 256, 0, stream>>>(PRE1, GXb, Wq, Whh, bih, bhh, out, hstate,
                                          pbuf, cnt, t0, tc, t0 == 0 ? 1 : 0);
    t0 += tc;
  }
}

// Round 4
// 2797.749 us; speedup vs baseline: 1.4272x; 1.0766x over previous
//
#include <hip/hip_runtime.h>
#include <cstddef>

#define TSTEPS 128
#define BATCH  256
#define DIN    600
#define NR     6
#define KACT   4
#define DH     100
#define DK     64
#define DV     400
#define G3     300
#define LD1    512    // PRE1 row stride: [kx(64) | vx(400) | pad(48)]
#define LDG    1920   // GX row stride: [gi(1800) | pad(120)]

// ---------- W1[600][512] = [Wk | Wv | 0] ----------
__global__ __launch_bounds__(256) void build_w1(const float* __restrict__ Wk,
                                                const float* __restrict__ Wv,
                                                float* __restrict__ W1) {
  int idx = blockIdx.x * 256 + threadIdx.x;
  if (idx >= DIN * LD1) return;
  int d = idx >> 9, c = idx & (LD1 - 1);
  float v = 0.f;
  if (c < DK)            v = Wk[d * DK + c];
  else if (c < DK + DV)  v = Wv[d * DV + (c - DK)];
  W1[idx] = v;
}

// ---------- WT[400][1920]: WT[v][n*300+j] = W_ih[n][v][j], zero pad ----------
__global__ __launch_bounds__(256) void build_wt(const float* __restrict__ Wih,
                                                float* __restrict__ WT) {
  int idx = blockIdx.x * 256 + threadIdx.x;
  if (idx >= DV * LDG) return;
  int v = idx / LDG, c = idx - v * LDG;
  float w = 0.f;
  if (c < NR * G3) { int n = c / G3, j = c - n * G3; w = Wih[(n * DV + v) * G3 + j]; }
  WT[idx] = w;
}

// ---------- generic fp32 GEMM: C[M][ldc] = A[M][lda(K...)] * B[K][ldb] ----------
__global__ __launch_bounds__(256) void sgemm_k(const float* __restrict__ A, int lda,
                                               const float* __restrict__ B, int ldb,
                                               float* __restrict__ C, int ldc, int K) {
  __shared__ float As[8][132];
  __shared__ float Bs[8][128];
  const int tid = threadIdx.x;
  const int tx = tid & 15, ty = tid >> 4;
  const size_t m0 = (size_t)blockIdx.x * 128, n0 = (size_t)blockIdx.y * 128;
  const int arow = tid >> 1, akq = (tid & 1) * 4;
  const int brow = tid >> 5, bcol = (tid & 31) * 4;
  const float* Ap = A + (m0 + arow) * (size_t)lda + akq;
  const float* Bp = B + (size_t)brow * ldb + n0 + bcol;

  float acc[8][8];
#pragma unroll
  for (int i = 0; i < 8; ++i)
#pragma unroll
    for (int j = 0; j < 8; ++j) acc[i][j] = 0.f;

  for (int k0 = 0; k0 < K; k0 += 8) {
    float4 av = *(const float4*)(Ap + k0);
    float4 bv = *(const float4*)(Bp + (size_t)k0 * ldb);
    __syncthreads();
    As[akq + 0][arow] = av.x;
    As[akq + 1][arow] = av.y;
    As[akq + 2][arow] = av.z;
    As[akq + 3][arow] = av.w;
    *(float4*)&Bs[brow][bcol] = bv;
    __syncthreads();
#pragma unroll
    for (int k = 0; k < 8; ++k) {
      float a[8], b[8];
#pragma unroll
      for (int i = 0; i < 8; ++i) a[i] = As[k][ty * 8 + i];
#pragma unroll
      for (int j = 0; j < 8; ++j) b[j] = Bs[k][tx * 8 + j];
#pragma unroll
      for (int i = 0; i < 8; ++i)
#pragma unroll
        for (int j = 0; j < 8; ++j) acc[i][j] += a[i] * b[j];
    }
  }

  float* Cp = C + (m0 + (size_t)ty * 8) * ldc + n0 + tx * 8;
#pragma unroll
  for (int i = 0; i < 8; ++i) {
    float4 v0 = make_float4(acc[i][0], acc[i][1], acc[i][2], acc[i][3]);
    float4 v1 = make_float4(acc[i][4], acc[i][5], acc[i][6], acc[i][7]);
    *(float4*)(Cp + (size_t)i * ldc)     = v0;
    *(float4*)(Cp + (size_t)i * ldc + 4) = v1;
  }
}

// ---------- RIMs scan: block = (batch-group of 8, rim). 192 blocks ----------
// Transposed LDS weight layouts (ds_read_b128 along hh; h reads are float4
// broadcasts). Biases live in registers (loaded once from global — they are
// time-invariant; fixes the uninitialized-LDS-tail bug of rounds 2/3).
// Accumulation order kept bit-identical to rounds 1/2.
__global__ __launch_bounds__(256) void rim_scan(
    const float* __restrict__ PRE1, const float* __restrict__ GX,
    const float* __restrict__ Wq,   const float* __restrict__ Whh,
    const float* __restrict__ bih,  const float* __restrict__ bhh,
    float* __restrict__ out, float* __restrict__ hstate,
    float* __restrict__ pbuf, int* __restrict__ cnt,
    int t0, int tc, int first) {
  __shared__ __align__(16) float wbuf[G3 * DH];   // 120.0 KB  Whh[n] transposed [col][hh]
  __shared__ __align__(16) float wqbuf[DK * DH];  //  25.6 KB  Wq[n] transposed [k][hh]
  __shared__ __align__(16) float hbuf[8 * DH];    //   3.2 KB  h [b][hh]
  __shared__ __align__(16) float kxl[8][68];
  __shared__ __align__(16) float ql[8][68];
  __shared__ float pl[8][NR];

  const int tid = threadIdx.x;
  const int g = blockIdx.x & 31;   // batch group
  const int n = blockIdx.x >> 5;   // rim

  // ---- stage per-rim weights into LDS, transposed (once) ----
  {
    const float* wsrc = Whh + (size_t)n * (DH * G3);       // [hh][col]
    for (int i = tid; i < DH * G3; i += 256) {
      int hh = i / G3, c = i - hh * G3;
      wbuf[c * DH + hh] = wsrc[i];
    }
    const float* qsrc = Wq + (size_t)n * (DH * DK);        // [hh][k]
    for (int i = tid; i < DH * DK; i += 256) {
      int hh = i >> 6, k = i & 63;
      wqbuf[k * DH + hh] = qsrc[i];
    }
    if (first) {
      for (int i = tid; i < 8 * DH; i += 256) hbuf[i] = 0.f;
    } else {
      for (int i = tid; i < 8 * DH; i += 256) {
        int b = i / DH, hh = i - b * DH;
        hbuf[b * DH + hh] = hstate[((size_t)(g * 8 + b) * NR + n) * DH + hh];
      }
    }
  }
  __syncthreads();

  const int half = tid >> 7;       // 0/1 -> batches 0-3 / 4-7
  const int ho = tid & 127;        // output hidden index (valid < 100)
  const bool act_t = ho < DH;
  const int bbase = half * 4;
  const int kq = tid & 63, bp = tid >> 6;  // q-phase mapping

  // ---- biases -> registers, once (time-invariant; guarded against OOB) ----
  float bi0 = 0.f, bi1 = 0.f, bi2 = 0.f, bh0 = 0.f, bh1 = 0.f, bh2 = 0.f;
  if (act_t) {
    const float* bi = bih + (size_t)n * G3 + ho;
    const float* bh = bhh + (size_t)n * G3 + ho;
    bi0 = bi[0]; bi1 = bi[DH]; bi2 = bi[2 * DH];
    bh0 = bh[0]; bh1 = bh[DH]; bh2 = bh[2 * DH];
  }

  const float4* wr = (const float4*)&wbuf[ho * DH];
  const float4* wz = (const float4*)&wbuf[(ho + 100) * DH];
  const float4* wn = (const float4*)&wbuf[(ho + 200) * DH];
  const float4* wq4 = (const float4*)&wqbuf[kq * DH];
  const float4* h40 = (const float4*)&hbuf[(bbase + 0) * DH];
  const float4* h41 = (const float4*)&hbuf[(bbase + 1) * DH];
  const float4* h42 = (const float4*)&hbuf[(bbase + 2) * DH];
  const float4* h43 = (const float4*)&hbuf[(bbase + 3) * DH];
  const float4* hq0 = (const float4*)&hbuf[bp * DH];
  const float4* hq1 = (const float4*)&hbuf[(bp + 4) * DH];

  for (int tl = 0; tl < tc; ++tl) {
    const int t = t0 + tl;
    const int par = t & 1;

    // ---- prefetch this step's GX rows into registers (consumed in GRU) ----
    float gx[4][3];
    if (act_t) {
#pragma unroll
      for (int b = 0; b < 4; ++b) {
        const float* gr = GX + ((size_t)tl * BATCH + g * 8 + bbase + b) * LDG + n * G3;
        gx[b][0] = gr[ho]; gx[b][1] = gr[ho + DH]; gx[b][2] = gr[ho + 2 * DH];
      }
    }

    // ---- kx load + q = h @ Wq (bit-identical hh order; float4 reads) ----
    kxl[bp][kq]     = PRE1[((size_t)tl * BATCH + g * 8 + bp) * LD1 + kq];
    kxl[bp + 4][kq] = PRE1[((size_t)tl * BATCH + g * 8 + bp + 4) * LD1 + kq];
    {
      float a0 = 0.f, a1 = 0.f;
#pragma unroll 5
      for (int q4 = 0; q4 < 25; ++q4) {
        float4 w = wq4[q4];
        float4 v0 = hq0[q4];
        float4 v1 = hq1[q4];
        a0 += v0.x * w.x; a0 += v0.y * w.y; a0 += v0.z * w.z; a0 += v0.w * w.w;
        a1 += v1.x * w.x; a1 += v1.y * w.y; a1 += v1.z * w.z; a1 += v1.w * w.w;
      }
      ql[bp][kq] = a0; ql[bp + 4][kq] = a1;
    }
    __syncthreads();

    // ---- score -> p_in, publish to peers (serial dot: bit-identical) ----
    if (tid < 8) {
      float s = 0.f;
      for (int k = 0; k < DK; ++k) s += ql[tid][k] * kxl[tid][k];
      s *= 0.125f;
      float m = s > 0.f ? s : 0.f;
      float e0 = expf(s - m), e1 = expf(-m);
      float p = e0 / (e0 + e1);
      __hip_atomic_store(&pbuf[((par * 32 + g) * NR + n) * 8 + tid], p,
                         __ATOMIC_RELAXED, __HIP_MEMORY_SCOPE_AGENT);
    }
    if (tid == 0) {
      __threadfence();
      __hip_atomic_fetch_add(&cnt[g], 1, __ATOMIC_RELEASE, __HIP_MEMORY_SCOPE_AGENT);
    }

    // ---- gh = h @ Whh from LDS (b128 weight reads, h broadcasts; overlaps sync) ----
    float acc[4][3];
#pragma unroll
    for (int b = 0; b < 4; ++b) { acc[b][0] = 0.f; acc[b][1] = 0.f; acc[b][2] = 0.f; }
    if (act_t) {
#pragma unroll 5
      for (int q4 = 0; q4 < 25; ++q4) {
        float4 w0 = wr[q4], w1 = wz[q4], w2 = wn[q4];
        float4 v0 = h40[q4], v1 = h41[q4], v2 = h42[q4], v3 = h43[q4];
        acc[0][0] += v0.x*w0.x; acc[0][0] += v0.y*w0.y; acc[0][0] += v0.z*w0.z; acc[0][0] += v0.w*w0.w;
        acc[0][1] += v0.x*w1.x; acc[0][1] += v0.y*w1.y; acc[0][1] += v0.z*w1.z; acc[0][1] += v0.w*w1.w;
        acc[0][2] += v0.x*w2.x; acc[0][2] += v0.y*w2.y; acc[0][2] += v0.z*w2.z; acc[0][2] += v0.w*w2.w;
        acc[1][0] += v1.x*w0.x; acc[1][0] += v1.y*w0.y; acc[1][0] += v1.z*w0.z; acc[1][0] += v1.w*w0.w;
        acc[1][1] += v1.x*w1.x; acc[1][1] += v1.y*w1.y; acc[1][1] += v1.z*w1.z; acc[1][1] += v1.w*w1.w;
        acc[1][2] += v1.x*w2.x; acc[1][2] += v1.y*w2.y; acc[1][2] += v1.z*w2.z; acc[1][2] += v1.w*w2.w;
        acc[2][0] += v2.x*w0.x; acc[2][0] += v2.y*w0.y; acc[2][0] += v2.z*w0.z; acc[2][0] += v2.w*w0.w;
        acc[2][1] += v2.x*w1.x; acc[2][1] += v2.y*w1.y; acc[2][1] += v2.z*w1.z; acc[2][1] += v2.w*w1.w;
        acc[2][2] += v2.x*w2.x; acc[2][2] += v2.y*w2.y; acc[2][2] += v2.z*w2.z; acc[2][2] += v2.w*w2.w;
        acc[3][0] += v3.x*w0.x; acc[3][0] += v3.y*w0.y; acc[3][0] += v3.z*w0.z; acc[3][0] += v3.w*w0.w;
        acc[3][1] += v3.x*w1.x; acc[3][1] += v3.y*w1.y; acc[3][1] += v3.z*w1.z; acc[3][1] += v3.w*w1.w;
        acc[3][2] += v3.x*w2.x; acc[3][2] += v3.y*w2.y; acc[3][2] += v3.z*w2.z; acc[3][2] += v3.w*w2.w;
      }
    }

    // ---- wave 0 waits for all 6 rims of this group, gathers p ----
    if (tid < 64) {
      const int target = 6 * (t + 1);
      while (__hip_atomic_load(&cnt[g], __ATOMIC_ACQUIRE, __HIP_MEMORY_SCOPE_AGENT) < target)
        __builtin_amdgcn_s_sleep(2);
      if (tid < 48) {
        int b = tid & 7, r = tid >> 3;
        pl[b][r] = __hip_atomic_load(&pbuf[((par * 32 + g) * NR + r) * 8 + b],
                                     __ATOMIC_RELAXED, __HIP_MEMORY_SCOPE_AGENT);
      }
    }
    __syncthreads();

    // ---- top-k mask + GRU pointwise + state update ----
    if (act_t) {
#pragma unroll
      for (int b = 0; b < 4; ++b) {
        const int bb = bbase + b;
        float p = pl[bb][n];
        int c = 0;
#pragma unroll
        for (int r = 0; r < NR; ++r) {
          float q = pl[bb][r];
          if (q > p || (q == p && r < n)) ++c;
        }
        float m = (c < KACT) ? 1.f : 0.f;
        float grv = acc[b][0] + bh0;
        float gzv = acc[b][1] + bh1;
        float gnv = acc[b][2] + bh2;
        float ir  = p * gx[b][0] + bi0;
        float iz  = p * gx[b][1] + bi1;
        float inn = p * gx[b][2] + bi2;
        float rr = 1.f / (1.f + expf(-(ir + grv)));
        float zz = 1.f / (1.f + expf(-(iz + gzv)));
        float nn = tanhf(inn + rr * gnv);
        float hprev = hbuf[bb * DH + ho];
        float hnew = (1.f - zz) * nn + zz * hprev;
        out[(((size_t)t * BATCH + g * 8 + bb) * NR + n) * DH + ho] = m * hnew;
        hbuf[bb * DH + ho] = (m > 0.f) ? hnew : hprev;
      }
    }
    __syncthreads();
  }

  for (int i = tid; i < 8 * DH; i += 256) {
    int b = i / DH, hh = i - b * DH;
    hstate[((size_t)(g * 8 + b) * NR + n) * DH + hh] = hbuf[b * DH + hh];
  }
}

extern "C" void kernel_launch(void* const* d_in, const int* in_sizes, int n_in,
                              void* d_out, int out_size, void* d_ws, size_t ws_size,
                              hipStream_t stream) {
  const float* x   = (const float*)d_in[0];
  const float* Wq  = (const float*)d_in[1];
  const float* Wk  = (const float*)d_in[2];
  const float* Wv  = (const float*)d_in[3];
  const float* Wih = (const float*)d_in[4];
  const float* Whh = (const float*)d_in[5];
  const float* bih = (const float*)d_in[6];
  const float* bhh = (const float*)d_in[7];
  float* out = (float*)d_out;
  char* ws = (char*)d_ws;

  const size_t W1_BYTES   = (size_t)DIN * LD1 * 4;     // 1,228,800
  const size_t WT_BYTES   = (size_t)DV * LDG * 4;      // 3,072,000
  const size_t H_BYTES    = (size_t)BATCH * 600 * 4;   //   614,400
  const size_t CNT_BYTES  = 256;                       // 32 ints, padded
  const size_t PBUF_BYTES = 2 * 32 * NR * 8 * 4;       //    12,288
  const size_t FIXED = W1_BYTES + WT_BYTES + H_BYTES + CNT_BYTES + PBUF_BYTES;
  const size_t PER_STEP = (size_t)BATCH * (LD1 + LDG) * 4;  // 2,490,368

  float* W1     = (float*)ws;
  float* WT     = (float*)(ws + W1_BYTES);
  float* hstate = (float*)(ws + W1_BYTES + WT_BYTES);
  int*   cnt    = (int*)  (ws + W1_BYTES + WT_BYTES + H_BYTES);
  float* pbuf   = (float*)(ws + W1_BYTES + WT_BYTES + H_BYTES + CNT_BYTES);

  long long avail = (long long)ws_size - (long long)FIXED;
  int TC = 1;
  if (avail > 0) {
    long long t = avail / (long long)PER_STEP;
    TC = (int)(t < 1 ? 1 : (t > TSTEPS ? TSTEPS : t));
  }
  float* PRE1 = (float*)(ws + FIXED);
  float* GXb  = (float*)(ws + FIXED + (size_t)TC * BATCH * LD1 * 4);

  hipMemsetAsync(cnt, 0, CNT_BYTES, stream);
  build_w1<<<(DIN * LD1) / 256, 256, 0, stream>>>(Wk, Wv, W1);
  build_wt<<<(DV * LDG) / 256, 256, 0, stream>>>(Wih, WT);

  for (int t0 = 0; t0 < TSTEPS; ) {
    int tc = TSTEPS - t0 < TC ? TSTEPS - t0 : TC;
    dim3 g1(tc * 2, LD1 / 128);
    sgemm_k<<<g1, 256, 0, stream>>>(x + (size_t)t0 * BATCH * DIN, DIN, W1, LD1, PRE1, LD1, DIN);
    dim3 g2(tc * 2, LDG / 128);
    sgemm_k<<<g2, 256, 0, stream>>>(PRE1 + DK, LD1, WT, LDG, GXb, LDG, DV);
    rim_scan<<<32 * NR, 256, 0, stream>>>(PRE1, GXb, Wq, Whh, bih, bhh, out, hstate,
                                          pbuf, cnt, t0, tc, t0 == 0 ? 1 : 0);
    t0 += tc;
  }
}